// Round 1
// baseline (247.662 us; speedup 1.0000x reference)
//
#include <hip/hip_runtime.h>
#include <math.h>

// ---------------------------------------------------------------------------
// PredictiveModule: 3-layer MLP matvec chain + gate + logprob + top-k(512)
//
// Numerics: all matvecs accumulate in f64 (memory-bound kernel, f64 FMA is
// free) so our pre-activations sit ~1e-13 from truth; top-k order-statistic
// gaps are ~3e-5 so f32-accumulation drift (~1e-5) risks boundary swaps.
// The f32 rounding of the reference is mimicked only at sample = am + 0.05*n.
// ---------------------------------------------------------------------------

#define F64_ATOMIC_ADD(p, v) unsafeAtomicAdd((p), (v))

// y[n] (+)= sum_{k in chunk} x_k * W[k][n]   (W row-major K x N)
// mode: xf != nullptr -> x_k = xf[k]  (layer 1, raw ct)
//       else          -> x_k = relu(xpre[k] + xbias[k])
__global__ __launch_bounds__(256) void k_matvec(
    const float* __restrict__ W, int N,
    const float* __restrict__ xf,
    const double* __restrict__ xpre,
    const float* __restrict__ xbias,
    double* __restrict__ y,
    int kchunk)
{
    const int col = (blockIdx.x * blockDim.x + threadIdx.x) * 4;
    const int k0 = blockIdx.y * kchunk;
    const float* Wp = W + (size_t)k0 * (size_t)N + col;
    double a0 = 0.0, a1 = 0.0, a2 = 0.0, a3 = 0.0;
    for (int kk = 0; kk < kchunk; ++kk) {
        const int k = k0 + kk;
        double x;
        if (xf) {
            x = (double)xf[k];
        } else {
            double t = xpre[k] + (double)xbias[k];
            x = t > 0.0 ? t : 0.0;
        }
        const float4 w = *reinterpret_cast<const float4*>(Wp);
        a0 += x * (double)w.x;
        a1 += x * (double)w.y;
        a2 += x * (double)w.z;
        a3 += x * (double)w.w;
        Wp += N;
    }
    F64_ATOMIC_ADD(&y[col + 0], a0);
    F64_ATOMIC_ADD(&y[col + 1], a1);
    F64_ATOMIC_ADD(&y[col + 2], a2);
    F64_ATOMIC_ADD(&y[col + 3], a3);
}

__inline__ __device__ double waveReduceSum(double v) {
    for (int o = 32; o > 0; o >>= 1) v += __shfl_down(v, o, 64);
    return v;
}

// Per-element: vm = clip(vmpre + b3, +-100); gate = sigmoid(qm*ct);
// am = clip(gate*vm, +-1000); sample = f32(am_f32 + 0.05f*noise).
// Accumulates sum((sample-am)/0.05)^2 into *lp.
__global__ __launch_bounds__(256) void k_finalize(
    const double* __restrict__ vmpre,
    const float* __restrict__ b3,
    const float* __restrict__ qm,
    const float* __restrict__ ct,
    const float* __restrict__ noise,
    float* __restrict__ samp,
    double* __restrict__ lp,
    int D)
{
    const int i = blockIdx.x * blockDim.x + threadIdx.x;
    double term = 0.0;
    if (i < D) {
        double vm = vmpre[i] + (double)b3[i];
        vm = vm > 100.0 ? 100.0 : (vm < -100.0 ? -100.0 : vm);
        double z = (double)qm[i] * (double)ct[i];
        double g = 1.0 / (1.0 + exp(-z));
        double am = g * vm;  // influence == 1.0 exactly
        am = am > 1000.0 ? 1000.0 : (am < -1000.0 ? -1000.0 : am);
        float amf = (float)am;
        float s = amf + 0.05f * noise[i];
        samp[i] = s;
        float df = (s - amf) / 0.05f;
        term = (double)df * (double)df;
    }
    double w = waveReduceSum(term);
    __shared__ double red[4];
    const int lane = threadIdx.x & 63, wid = threadIdx.x >> 6;
    if (lane == 0) red[wid] = w;
    __syncthreads();
    if (threadIdx.x == 0) {
        F64_ATOMIC_ADD(lp, red[0] + red[1] + red[2] + red[3]);
    }
}

// Single-block top-k: radix-select (MSB-first, 4x 256-bin passes) on the
// uint-encoded |sample| (monotonic for non-negative floats), stable tie-break
// by ascending index (matches jax.lax.top_k). Writes all D outputs + logprob.
#define TPK 1024
__global__ __launch_bounds__(TPK) void k_topk(
    const float* __restrict__ samp,
    const int* __restrict__ kptr,
    const double* __restrict__ lp,
    float* __restrict__ out,
    int D)
{
    __shared__ uint32_t u[16384];
    __shared__ int hist[256];
    __shared__ int tsum[TPK];
    __shared__ uint32_t s_prefix;
    __shared__ int s_kk;

    const int t = threadIdx.x;
    for (int i = t; i < D; i += TPK)
        u[i] = __float_as_uint(samp[i]) & 0x7fffffffu;
    __syncthreads();

    const int k = *kptr;
    uint32_t prefix = 0;
    int kk = k;
    for (int pass = 0; pass < 4; ++pass) {
        const int shift = 24 - 8 * pass;
        const uint32_t done_mask = (pass == 0) ? 0u : (0xffffffffu << (32 - 8 * pass));
        if (t < 256) hist[t] = 0;
        __syncthreads();
        for (int i = t; i < D; i += TPK) {
            const uint32_t v = u[i];
            if ((v & done_mask) == prefix)
                atomicAdd(&hist[(v >> shift) & 0xff], 1);
        }
        __syncthreads();
        if (t == 0) {
            int c = 0, b = 255;
            for (; b >= 0; --b) { c += hist[b]; if (c >= kk) break; }
            s_kk = kk - (c - hist[b]);              // remaining among == bin b
            s_prefix = prefix | ((uint32_t)b << shift);
        }
        __syncthreads();
        prefix = s_prefix;
        kk = s_kk;
        __syncthreads();
    }
    const uint32_t vstar = prefix;
    const int need = kk;  // how many ties (lowest index) to keep

    // stable prefix over equals: contiguous chunks preserve index order
    const int per = D / TPK;
    const int base = t * per;
    int cnt = 0;
    for (int j = 0; j < per; ++j) cnt += (u[base + j] == vstar) ? 1 : 0;
    tsum[t] = cnt;
    __syncthreads();
    for (int off = 1; off < TPK; off <<= 1) {
        int v = tsum[t];
        int add = (t >= off) ? tsum[t - off] : 0;
        __syncthreads();
        tsum[t] = v + add;
        __syncthreads();
    }
    int offset = tsum[t] - cnt;  // exclusive prefix of equals before my chunk
    for (int j = 0; j < per; ++j) {
        const int i = base + j;
        const uint32_t v = u[i];
        float o = 0.0f;
        if (v > vstar) {
            o = samp[i];
        } else if (v == vstar) {
            if (offset < need) o = samp[i];
            offset++;
        }
        out[i] = o;
    }

    if (t == 0) {
        const double S = *lp;
        const double c = -log(0.05) - 0.5 * log(2.0 * M_PI);
        out[D] = (float)(-0.5 * S + (double)D * c);
    }
}

extern "C" void kernel_launch(void* const* d_in, const int* in_sizes, int n_in,
                              void* d_out, int out_size, void* d_ws, size_t ws_size,
                              hipStream_t stream) {
    const float* ct    = (const float*)d_in[0];
    const float* W1    = (const float*)d_in[1];
    const float* b1    = (const float*)d_in[2];
    const float* W2    = (const float*)d_in[3];
    const float* b2    = (const float*)d_in[4];
    const float* W3    = (const float*)d_in[5];
    const float* b3    = (const float*)d_in[6];
    const float* qm    = (const float*)d_in[7];
    const float* noise = (const float*)d_in[8];
    const int*   kp    = (const int*)d_in[9];

    const int D = in_sizes[0];   // 16384
    const int H = in_sizes[2];   // 4096

    // ws layout: h1pre[H] f64 | h2pre[H] f64 | vmpre[D] f64 | samp[D] f32 | lp f64
    double* h1  = (double*)d_ws;
    double* h2  = h1 + H;
    double* vmp = h2 + H;
    float*  smp = (float*)(vmp + D);
    double* lp  = (double*)(smp + D);
    const size_t zero_bytes = (size_t)(2 * H + D) * 8 + (size_t)D * 4 + 8;
    hipMemsetAsync(d_ws, 0, zero_bytes, stream);

    // Layer 1: K=D, N=H, x = ct
    {
        const int kchunk = 64;
        dim3 grid(H / 1024, D / kchunk);
        k_matvec<<<grid, 256, 0, stream>>>(W1, H, ct, nullptr, nullptr, h1, kchunk);
    }
    // Layer 2: K=H, N=H, x = relu(h1 + b1)
    {
        const int kchunk = 32;
        dim3 grid(H / 1024, H / kchunk);
        k_matvec<<<grid, 256, 0, stream>>>(W2, H, nullptr, h1, b1, h2, kchunk);
    }
    // Layer 3: K=H, N=D, x = relu(h2 + b2)
    {
        const int kchunk = 64;
        dim3 grid(D / 1024, H / kchunk);
        k_matvec<<<grid, 256, 0, stream>>>(W3, D, nullptr, h2, b2, vmp, kchunk);
    }
    // Elementwise + logprob partial sums
    k_finalize<<<dim3(D / 256), 256, 0, stream>>>(vmp, b3, qm, ct, noise, smp, lp, D);
    // Top-k select + write all outputs
    k_topk<<<dim3(1), TPK, 0, stream>>>(smp, kp, lp, (float*)d_out, D);
}

// Round 2
// 218.700 us; speedup vs baseline: 1.1324x; 1.1324x over previous
//
#include <hip/hip_runtime.h>
#include <math.h>

// ---------------------------------------------------------------------------
// PredictiveModule: 3-layer MLP matvec chain + gate + logprob + top-k(512)
//
// Structure (atomic-free split-K):
//   k_matvec<KCHUNK,CP>: grid (N/(1024*CP), K/KCHUNK). Block (x,y) computes
//   partial dot-products of rows [y*KCHUNK, ...) against its 1024*CP columns
//   and writes f64 partials to p[y][cols]. The NEXT layer's blocks reduce the
//   partials for their x-chunk cooperatively in a prologue (LLC-resident).
//   No atomics, no memset; every ws byte we read is written first.
//
// Numerics: f64 accumulation everywhere (memory-bound; f64 FMA is free) so
// pre-activations sit ~1e-13 from truth; top-k order-statistic gaps are ~3e-5
// so f32 drift risks boundary swaps. f32 rounding mimicked only at
// sample = f32(am) + 0.05f*noise, as in the reference.
// ---------------------------------------------------------------------------

template<int KCHUNK, int CP>
__global__ __launch_bounds__(256) void k_matvec(
    const float* __restrict__ W, int N, int K,
    const float* __restrict__ xf,          // layer 1: raw ct (f32); else null
    const double* __restrict__ xpart,      // partials [Gprev][K]; null for L1
    int Gprev,
    const float* __restrict__ xbias,       // bias for relu (null for L1)
    double* __restrict__ ypart)            // out partials [gridDim.y][N]
{
    __shared__ double xs[KCHUNK];
    __shared__ double xred[256];
    const int t = threadIdx.x;
    const int k0 = blockIdx.y * KCHUNK;

    if (xf) {
        if (t < KCHUNK) xs[t] = (double)xf[k0 + t];
    } else {
        // cooperative reduce of previous layer's partials for our x-chunk
        constexpr int NS = 256 / KCHUNK;   // g-slices
        const int kl = t & (KCHUNK - 1);
        const int sl = t / KCHUNK;
        double s = 0.0;
        for (int g = sl; g < Gprev; g += NS)
            s += xpart[(size_t)g * K + k0 + kl];
        xred[t] = s;
        __syncthreads();
        if (t < KCHUNK) {
            double tot = (double)xbias[k0 + t];
            #pragma unroll
            for (int s2 = 0; s2 < NS; ++s2) tot += xred[s2 * KCHUNK + t];
            xs[t] = tot > 0.0 ? tot : 0.0;  // relu
        }
    }
    __syncthreads();

    const int colbase = blockIdx.x * (1024 * CP) + t * 4;
    const float* Wp = W + (size_t)k0 * (size_t)N + colbase;
    double acc[CP][4];
    #pragma unroll
    for (int c = 0; c < CP; ++c)
        #pragma unroll
        for (int j = 0; j < 4; ++j) acc[c][j] = 0.0;

    #pragma unroll 8
    for (int kk = 0; kk < KCHUNK; ++kk) {
        const double x = xs[kk];
        #pragma unroll
        for (int c = 0; c < CP; ++c) {
            const float4 w = *reinterpret_cast<const float4*>(Wp + (size_t)kk * N + c * 1024);
            acc[c][0] += x * (double)w.x;
            acc[c][1] += x * (double)w.y;
            acc[c][2] += x * (double)w.z;
            acc[c][3] += x * (double)w.w;
        }
    }

    double* yp = ypart + (size_t)blockIdx.y * (size_t)N + colbase;
    #pragma unroll
    for (int c = 0; c < CP; ++c) {
        *reinterpret_cast<double2*>(yp + c * 1024 + 0) = make_double2(acc[c][0], acc[c][1]);
        *reinterpret_cast<double2*>(yp + c * 1024 + 2) = make_double2(acc[c][2], acc[c][3]);
    }
}

__inline__ __device__ double waveReduceSum(double v) {
    for (int o = 32; o > 0; o >>= 1) v += __shfl_down(v, o, 64);
    return v;
}

// Reduce layer-3 partials; vm = clip(sum + b3, +-100); gate = sigmoid(qm*ct);
// am = clip(gate*vm, +-1000); sample = f32(am) + 0.05f*noise.
// Per-block logprob partial -> lpp[blockIdx.x].
__global__ __launch_bounds__(256) void k_finalize(
    const double* __restrict__ p3, int G,
    const float* __restrict__ b3,
    const float* __restrict__ qm,
    const float* __restrict__ ct,
    const float* __restrict__ noise,
    float* __restrict__ samp,
    double* __restrict__ lpp,
    int D)
{
    const int i = blockIdx.x * 256 + threadIdx.x;
    double term = 0.0;
    if (i < D) {
        double vm = (double)b3[i];
        for (int g = 0; g < G; ++g) vm += p3[(size_t)g * D + i];
        vm = vm > 100.0 ? 100.0 : (vm < -100.0 ? -100.0 : vm);
        double z = (double)qm[i] * (double)ct[i];
        double g = 1.0 / (1.0 + exp(-z));
        double am = g * vm;  // influence == 1.0 exactly
        am = am > 1000.0 ? 1000.0 : (am < -1000.0 ? -1000.0 : am);
        float amf = (float)am;
        float s = amf + 0.05f * noise[i];
        samp[i] = s;
        float df = (s - amf) / 0.05f;
        term = (double)df * (double)df;
    }
    double w = waveReduceSum(term);
    __shared__ double red[4];
    const int lane = threadIdx.x & 63, wid = threadIdx.x >> 6;
    if (lane == 0) red[wid] = w;
    __syncthreads();
    if (threadIdx.x == 0)
        lpp[blockIdx.x] = red[0] + red[1] + red[2] + red[3];
}

// Single-block top-k: radix-select (MSB-first, 4x 256-bin passes) on the
// uint-encoded |sample| (monotonic for non-negative floats), stable tie-break
// by ascending index (matches jax.lax.top_k). Writes all D outputs + logprob.
#define TPK 1024
__global__ __launch_bounds__(TPK) void k_topk(
    const float* __restrict__ samp,
    const int* __restrict__ kptr,
    const double* __restrict__ lpp, int GLP,
    float* __restrict__ out,
    int D)
{
    __shared__ uint32_t u[16384];
    __shared__ int hist[256];
    __shared__ int tsum[TPK];
    __shared__ uint32_t s_prefix;
    __shared__ int s_kk;

    const int t = threadIdx.x;
    for (int i = t; i < D; i += TPK)
        u[i] = __float_as_uint(samp[i]) & 0x7fffffffu;
    __syncthreads();

    const int k = *kptr;
    uint32_t prefix = 0;
    int kk = k;
    for (int pass = 0; pass < 4; ++pass) {
        const int shift = 24 - 8 * pass;
        const uint32_t done_mask = (pass == 0) ? 0u : (0xffffffffu << (32 - 8 * pass));
        if (t < 256) hist[t] = 0;
        __syncthreads();
        for (int i = t; i < D; i += TPK) {
            const uint32_t v = u[i];
            if ((v & done_mask) == prefix)
                atomicAdd(&hist[(v >> shift) & 0xff], 1);
        }
        __syncthreads();
        if (t == 0) {
            int c = 0, b = 255;
            for (; b >= 0; --b) { c += hist[b]; if (c >= kk) break; }
            s_kk = kk - (c - hist[b]);              // remaining among == bin b
            s_prefix = prefix | ((uint32_t)b << shift);
        }
        __syncthreads();
        prefix = s_prefix;
        kk = s_kk;
        __syncthreads();
    }
    const uint32_t vstar = prefix;
    const int need = kk;  // how many ties (lowest index) to keep

    // stable prefix over equals: contiguous chunks preserve index order
    const int per = D / TPK;
    const int base = t * per;
    int cnt = 0;
    for (int j = 0; j < per; ++j) cnt += (u[base + j] == vstar) ? 1 : 0;
    tsum[t] = cnt;
    __syncthreads();
    for (int off = 1; off < TPK; off <<= 1) {
        int v = tsum[t];
        int add = (t >= off) ? tsum[t - off] : 0;
        __syncthreads();
        tsum[t] = v + add;
        __syncthreads();
    }
    int offset = tsum[t] - cnt;  // exclusive prefix of equals before my chunk
    for (int j = 0; j < per; ++j) {
        const int i = base + j;
        const uint32_t v = u[i];
        float o = 0.0f;
        if (v > vstar) {
            o = samp[i];
        } else if (v == vstar) {
            if (offset < need) o = samp[i];
            offset++;
        }
        out[i] = o;
    }

    if (t == 0) {
        double S = 0.0;
        for (int g = 0; g < GLP; ++g) S += lpp[g];
        const double c = -log(0.05) - 0.5 * log(2.0 * M_PI);
        out[D] = (float)(-0.5 * S + (double)D * c);
    }
}

extern "C" void kernel_launch(void* const* d_in, const int* in_sizes, int n_in,
                              void* d_out, int out_size, void* d_ws, size_t ws_size,
                              hipStream_t stream) {
    const float* ct    = (const float*)d_in[0];
    const float* W1    = (const float*)d_in[1];
    const float* b1    = (const float*)d_in[2];
    const float* W2    = (const float*)d_in[3];
    const float* b2    = (const float*)d_in[4];
    const float* W3    = (const float*)d_in[5];
    const float* b3    = (const float*)d_in[6];
    const float* qm    = (const float*)d_in[7];
    const float* noise = (const float*)d_in[8];
    const int*   kp    = (const int*)d_in[9];

    const int D = in_sizes[0];   // 16384
    const int H = in_sizes[2];   // 4096

    // grid geometry (split-K partial groups)
    const int G1 = D / 64;       // 256  (L1: KCHUNK=64)
    const int G2 = H / 32;       // 128  (L2: KCHUNK=32)
    const int G3 = H / 64;       // 64   (L3: KCHUNK=64)
    const int GLP = D / 256;     // 64   finalize blocks

    // ws layout: p1[G1][H] | p2[G2][H] | p3[G3][D] | samp[D] f32 | lpp[GLP]
    double* p1  = (double*)d_ws;
    double* p2  = p1 + (size_t)G1 * H;
    double* p3  = p2 + (size_t)G2 * H;
    float*  smp = (float*)(p3 + (size_t)G3 * D);
    double* lpp = (double*)(smp + D);   // D*4 bytes keeps 8B alignment

    // Layer 1: K=D, N=H, x = ct
    k_matvec<64, 2><<<dim3(H / 2048, G1), 256, 0, stream>>>(
        W1, H, D, ct, nullptr, 0, nullptr, p1);
    // Layer 2: K=H, N=H, x = relu(reduce(p1) + b1)
    k_matvec<32, 1><<<dim3(H / 1024, G2), 256, 0, stream>>>(
        W2, H, H, nullptr, p1, G1, b1, p2);
    // Layer 3: K=H, N=D, x = relu(reduce(p2) + b2)
    k_matvec<64, 2><<<dim3(D / 2048, G3), 256, 0, stream>>>(
        W3, D, H, nullptr, p2, G2, b2, p3);
    // Reduce p3 + elementwise + per-block logprob partials
    k_finalize<<<dim3(GLP), 256, 0, stream>>>(
        p3, G3, b3, qm, ct, noise, smp, lpp, D);
    // Top-k select + write all outputs (+ logprob sum)
    k_topk<<<dim3(1), TPK, 0, stream>>>(smp, kp, lpp, GLP, (float*)d_out, D);
}

// Round 3
// 211.884 us; speedup vs baseline: 1.1689x; 1.0322x over previous
//
#include <hip/hip_runtime.h>
#include <math.h>

// ---------------------------------------------------------------------------
// PredictiveModule: 3-layer MLP matvec chain + gate + logprob + top-k(512)
//
// R3 changes vs R2 (theory: serial-scalar topk tail ~30-50us + grid-capped
// matvec occupancy):
//  - topk: per-wave privatized histograms (row-padded 257 ints -> conflict-
//    free cross-wave reduce), parallel suffix-scan + ballot bin-select
//    (replaces t==0 serial 256-iter LDS scan), wave-parallel logprob reduce
//    (replaces t==0 serial 64 global reads).
//  - matvec split-K doubled: KCHUNK 64->32 (L1,L3), 32->16 (L2) => 1024
//    blocks/layer = 4 blocks/CU = 16 waves/CU for latency hiding.
//
// Numerics: f64 accumulation everywhere (memory-bound; f64 is free) so
// pre-activations sit ~1e-13 from truth; top-k order-statistic gaps are ~3e-5
// so f32 drift risks boundary swaps. f32 rounding mimicked only at
// sample = f32(am) + 0.05f*noise, as in the reference.
// ---------------------------------------------------------------------------

template<int KCHUNK, int CP>
__global__ __launch_bounds__(256) void k_matvec(
    const float* __restrict__ W, int N, int K,
    const float* __restrict__ xf,          // layer 1: raw ct (f32); else null
    const double* __restrict__ xpart,      // partials [Gprev][K]; null for L1
    int Gprev,
    const float* __restrict__ xbias,       // bias for relu (null for L1)
    double* __restrict__ ypart)            // out partials [gridDim.y][N]
{
    __shared__ double xs[KCHUNK];
    __shared__ double xred[256];
    const int t = threadIdx.x;
    const int k0 = blockIdx.y * KCHUNK;

    if (xf) {
        if (t < KCHUNK) xs[t] = (double)xf[k0 + t];
    } else {
        // cooperative reduce of previous layer's partials for our x-chunk
        constexpr int NS = 256 / KCHUNK;   // g-slices
        const int kl = t & (KCHUNK - 1);
        const int sl = t / KCHUNK;
        double s = 0.0;
        for (int g = sl; g < Gprev; g += NS)
            s += xpart[(size_t)g * K + k0 + kl];
        xred[t] = s;
        __syncthreads();
        if (t < KCHUNK) {
            double tot = (double)xbias[k0 + t];
            #pragma unroll
            for (int s2 = 0; s2 < NS; ++s2) tot += xred[s2 * KCHUNK + t];
            xs[t] = tot > 0.0 ? tot : 0.0;  // relu
        }
    }
    __syncthreads();

    const int colbase = blockIdx.x * (1024 * CP) + t * 4;
    const float* Wp = W + (size_t)k0 * (size_t)N + colbase;
    double acc[CP][4];
    #pragma unroll
    for (int c = 0; c < CP; ++c)
        #pragma unroll
        for (int j = 0; j < 4; ++j) acc[c][j] = 0.0;

    #pragma unroll 8
    for (int kk = 0; kk < KCHUNK; ++kk) {
        const double x = xs[kk];
        #pragma unroll
        for (int c = 0; c < CP; ++c) {
            const float4 w = *reinterpret_cast<const float4*>(Wp + (size_t)kk * N + c * 1024);
            acc[c][0] += x * (double)w.x;
            acc[c][1] += x * (double)w.y;
            acc[c][2] += x * (double)w.z;
            acc[c][3] += x * (double)w.w;
        }
    }

    double* yp = ypart + (size_t)blockIdx.y * (size_t)N + colbase;
    #pragma unroll
    for (int c = 0; c < CP; ++c) {
        *reinterpret_cast<double2*>(yp + c * 1024 + 0) = make_double2(acc[c][0], acc[c][1]);
        *reinterpret_cast<double2*>(yp + c * 1024 + 2) = make_double2(acc[c][2], acc[c][3]);
    }
}

__inline__ __device__ double waveReduceSum(double v) {
    for (int o = 32; o > 0; o >>= 1) v += __shfl_down(v, o, 64);
    return v;
}

// Reduce layer-3 partials; vm = clip(sum + b3, +-100); gate = sigmoid(qm*ct);
// am = clip(gate*vm, +-1000); sample = f32(am) + 0.05f*noise.
// Per-block logprob partial -> lpp[blockIdx.x].
__global__ __launch_bounds__(256) void k_finalize(
    const double* __restrict__ p3, int G,
    const float* __restrict__ b3,
    const float* __restrict__ qm,
    const float* __restrict__ ct,
    const float* __restrict__ noise,
    float* __restrict__ samp,
    double* __restrict__ lpp,
    int D)
{
    const int i = blockIdx.x * 256 + threadIdx.x;
    double term = 0.0;
    if (i < D) {
        double vm = (double)b3[i];
        for (int g = 0; g < G; ++g) vm += p3[(size_t)g * D + i];
        vm = vm > 100.0 ? 100.0 : (vm < -100.0 ? -100.0 : vm);
        double z = (double)qm[i] * (double)ct[i];
        double g = 1.0 / (1.0 + exp(-z));
        double am = g * vm;  // influence == 1.0 exactly
        am = am > 1000.0 ? 1000.0 : (am < -1000.0 ? -1000.0 : am);
        float amf = (float)am;
        float s = amf + 0.05f * noise[i];
        samp[i] = s;
        float df = (s - amf) / 0.05f;
        term = (double)df * (double)df;
    }
    double w = waveReduceSum(term);
    __shared__ double red[4];
    const int lane = threadIdx.x & 63, wid = threadIdx.x >> 6;
    if (lane == 0) red[wid] = w;
    __syncthreads();
    if (threadIdx.x == 0)
        lpp[blockIdx.x] = red[0] + red[1] + red[2] + red[3];
}

// Single-block top-k: radix-select (MSB-first, 4x 256-bin passes) on the
// uint-encoded |sample| (monotonic for non-negative floats), stable tie-break
// by ascending index (matches jax.lax.top_k). Writes all D outputs + logprob.
// All scans parallelized: per-wave privatized histograms, suffix-scan +
// ballot-count bin selection, wave-parallel logprob sum.
#define TPK 1024
#define NW (TPK / 64)
__global__ __launch_bounds__(TPK) void k_topk(
    const float* __restrict__ samp,
    const int* __restrict__ kptr,
    const double* __restrict__ lpp, int GLP,
    float* __restrict__ out,
    int D)
{
    __shared__ uint32_t u[16384];
    __shared__ int whist[NW][257];      // 257: conflict-free cross-wave reduce
    __shared__ int hist[256];
    __shared__ int sfx[256];
    __shared__ int tsum[TPK];
    __shared__ int wcnt[4];
    __shared__ uint32_t s_prefix;
    __shared__ int s_kk;

    const int t = threadIdx.x;
    const int lane = t & 63;
    const int wid = t >> 6;

    for (int i = t; i < D; i += TPK)
        u[i] = __float_as_uint(samp[i]) & 0x7fffffffu;
    __syncthreads();

    const int k = *kptr;
    uint32_t prefix = 0;
    int kk = k;
    for (int pass = 0; pass < 4; ++pass) {
        const int shift = 24 - 8 * pass;
        const uint32_t done_mask = (pass == 0) ? 0u : (0xffffffffu << (32 - 8 * pass));
        for (int i = t; i < NW * 257; i += TPK) ((int*)whist)[i] = 0;
        __syncthreads();
        for (int i = t; i < D; i += TPK) {
            const uint32_t v = u[i];
            if ((v & done_mask) == prefix)
                atomicAdd(&whist[wid][(v >> shift) & 0xff], 1);
        }
        __syncthreads();
        if (t < 256) {
            int s = 0;
            #pragma unroll
            for (int w = 0; w < NW; ++w) s += whist[w][t];
            hist[t] = s;
            sfx[t] = s;
        }
        __syncthreads();
        // suffix sums: sfx[b] = hist[b] + ... + hist[255]
        #pragma unroll
        for (int off = 1; off < 256; off <<= 1) {
            int add = 0;
            if (t < 256 && t + off < 256) add = sfx[t + off];
            __syncthreads();
            if (t < 256) sfx[t] += add;
            __syncthreads();
        }
        // b* = (# of b with sfx[b] >= kk) - 1  (sfx is non-increasing in b)
        {
            bool cond = (t < 256) && (sfx[t] >= kk);
            unsigned long long m = __ballot(cond);
            if (lane == 0 && wid < 4) wcnt[wid] = __popcll(m);
            __syncthreads();
            if (t == 0) {
                int b = wcnt[0] + wcnt[1] + wcnt[2] + wcnt[3] - 1;
                s_kk = kk - (sfx[b] - hist[b]);      // remaining among == bin b
                s_prefix = prefix | ((uint32_t)b << shift);
            }
            __syncthreads();
        }
        prefix = s_prefix;
        kk = s_kk;
        __syncthreads();
    }
    const uint32_t vstar = prefix;
    const int need = kk;  // how many ties (lowest index) to keep

    // stable prefix over equals: contiguous chunks preserve index order
    const int per = D / TPK;
    const int base = t * per;
    int cnt = 0;
    for (int j = 0; j < per; ++j) cnt += (u[base + j] == vstar) ? 1 : 0;
    tsum[t] = cnt;
    __syncthreads();
    for (int off = 1; off < TPK; off <<= 1) {
        int v = tsum[t];
        int add = (t >= off) ? tsum[t - off] : 0;
        __syncthreads();
        tsum[t] = v + add;
        __syncthreads();
    }
    int offset = tsum[t] - cnt;  // exclusive prefix of equals before my chunk
    for (int j = 0; j < per; ++j) {
        const int i = base + j;
        const uint32_t v = u[i];
        float o = 0.0f;
        if (v > vstar) {
            o = samp[i];
        } else if (v == vstar) {
            if (offset < need) o = samp[i];
            offset++;
        }
        out[i] = o;
    }

    // logprob: wave 0 reduces the per-block partials
    if (wid == 0) {
        double s = 0.0;
        for (int g = lane; g < GLP; g += 64) s += lpp[g];
        s = waveReduceSum(s);
        if (lane == 0) {
            const double c = -log(0.05) - 0.5 * log(2.0 * M_PI);
            out[D] = (float)(-0.5 * s + (double)D * c);
        }
    }
}

extern "C" void kernel_launch(void* const* d_in, const int* in_sizes, int n_in,
                              void* d_out, int out_size, void* d_ws, size_t ws_size,
                              hipStream_t stream) {
    const float* ct    = (const float*)d_in[0];
    const float* W1    = (const float*)d_in[1];
    const float* b1    = (const float*)d_in[2];
    const float* W2    = (const float*)d_in[3];
    const float* b2    = (const float*)d_in[4];
    const float* W3    = (const float*)d_in[5];
    const float* b3    = (const float*)d_in[6];
    const float* qm    = (const float*)d_in[7];
    const float* noise = (const float*)d_in[8];
    const int*   kp    = (const int*)d_in[9];

    const int D = in_sizes[0];   // 16384
    const int H = in_sizes[2];   // 4096

    // split-K geometry: 1024 blocks per layer = 4 blocks/CU = 16 waves/CU
    const int KC1 = 32, KC2 = 16, KC3 = 32;
    const int G1 = D / KC1;      // 512
    const int G2 = H / KC2;      // 256
    const int G3 = H / KC3;      // 128
    const int GLP = D / 256;     // 64   finalize blocks

    // ws layout: p1[G1][H] | p2[G2][H] | p3[G3][D] | samp[D] f32 | lpp[GLP]
    double* p1  = (double*)d_ws;
    double* p2  = p1 + (size_t)G1 * H;
    double* p3  = p2 + (size_t)G2 * H;
    float*  smp = (float*)(p3 + (size_t)G3 * D);
    double* lpp = (double*)(smp + D);   // D*4 bytes keeps 8B alignment

    // Layer 1: K=D, N=H, x = ct
    k_matvec<KC1, 2><<<dim3(H / 2048, G1), 256, 0, stream>>>(
        W1, H, D, ct, nullptr, 0, nullptr, p1);
    // Layer 2: K=H, N=H, x = relu(reduce(p1) + b1)
    k_matvec<KC2, 1><<<dim3(H / 1024, G2), 256, 0, stream>>>(
        W2, H, H, nullptr, p1, G1, b1, p2);
    // Layer 3: K=H, N=D, x = relu(reduce(p2) + b2)
    k_matvec<KC3, 2><<<dim3(D / 2048, G3), 256, 0, stream>>>(
        W3, D, H, nullptr, p2, G2, b2, p3);
    // Reduce p3 + elementwise + per-block logprob partials
    k_finalize<<<dim3(GLP), 256, 0, stream>>>(
        p3, G3, b3, qm, ct, noise, smp, lpp, D);
    // Top-k select + write all outputs (+ logprob sum)
    k_topk<<<dim3(1), TPK, 0, stream>>>(smp, kp, lpp, GLP, (float*)d_out, D);
}